// Round 1
// baseline (740.401 us; speedup 1.0000x reference)
//
#include <hip/hip_runtime.h>
#include <math.h>

// Problem constants (B=32, T=4096, C_IN=768, CODE_DIM=3, MAX_LEVEL=15, BW=0.5)
#define N_ROWS   131072          // B*T
#define N_CIN    768
#define N_KDE    45              // 3*15
#define N_BLOCKS 1024
#define N_WAVES  (N_BLOCKS * 4)  // 4096 waves, 256-thread blocks
#define RPW      (N_ROWS / N_WAVES)  // 32 rows per wave

// ws layout (floats):
//   [0, 393216)              zc[row][c]           (131072*3)
//   [393216, 439296)         partials[l][block]   (45*1024)
//   [439296, 439341)         kde[l]               (45)
#define WS_ZC_OFF        0
#define WS_PART_OFF      (N_ROWS * 3)
#define WS_KDE_OFF       (WS_PART_OFF + N_KDE * N_BLOCKS)

// ---------------------------------------------------------------------------
// Kernel A: zc = z @ W_c + b_c per row; per-lane KDE accumulation.
// One wave per row per iteration; lane reads 3x float4 (coalesced).
// ---------------------------------------------------------------------------
__global__ __launch_bounds__(256)
void k_zc_kde(const float* __restrict__ z, const float* __restrict__ Wc,
              const float* __restrict__ bc, const float* __restrict__ centers,
              float* __restrict__ zc, float* __restrict__ partials)
{
    const int tid  = threadIdx.x;
    const int lane = tid & 63;
    const int wid  = tid >> 6;
    const int gw   = blockIdx.x * 4 + wid;

    // Preload W_c fragment: k = seg*256 + lane*4 + m  (W_c is [768][3] row-major)
    float wcr[3][4][3];
#pragma unroll
    for (int seg = 0; seg < 3; ++seg)
#pragma unroll
        for (int m = 0; m < 4; ++m) {
            const int k = seg * 256 + lane * 4 + m;
#pragma unroll
            for (int c = 0; c < 3; ++c) wcr[seg][m][c] = Wc[k * 3 + c];
        }
    const float bc0 = bc[0], bc1 = bc[1], bc2 = bc[2];

    const int   myc   = lane / 15;                          // valid for lane<45
    const float myctr = (lane < N_KDE) ? centers[lane] : 0.f;
    float acc = 0.f;

    for (int i = 0; i < RPW; ++i) {
        const int row = gw + N_WAVES * i;
        const float4* zr = (const float4*)(z + (size_t)row * N_CIN);
        float4 v[3];
        v[0] = zr[lane];
        v[1] = zr[64 + lane];
        v[2] = zr[128 + lane];

        float s0 = 0.f, s1 = 0.f, s2 = 0.f;
#pragma unroll
        for (int seg = 0; seg < 3; ++seg) {
            const float e[4] = {v[seg].x, v[seg].y, v[seg].z, v[seg].w};
#pragma unroll
            for (int m = 0; m < 4; ++m) {
                s0 = fmaf(e[m], wcr[seg][m][0], s0);
                s1 = fmaf(e[m], wcr[seg][m][1], s1);
                s2 = fmaf(e[m], wcr[seg][m][2], s2);
            }
        }
        // 64-lane butterfly reduce (all lanes end with the full sums)
#pragma unroll
        for (int off = 32; off > 0; off >>= 1) {
            s0 += __shfl_xor(s0, off);
            s1 += __shfl_xor(s1, off);
            s2 += __shfl_xor(s2, off);
        }
        s0 += bc0; s1 += bc1; s2 += bc2;

        if (lane < 3)
            zc[(size_t)row * 3 + lane] = (lane == 0) ? s0 : ((lane == 1) ? s1 : s2);

        if (lane < N_KDE) {
            const float zv = (myc == 0) ? s0 : ((myc == 1) ? s1 : s2);
            const float d  = myctr - zv;
            acc += expf(-2.0f * d * d);   // exp(-0.5*((c-z)/0.5)^2)
        }
    }

    __shared__ float sm[4 * N_KDE];
    if (lane < N_KDE) sm[wid * N_KDE + lane] = acc;
    __syncthreads();
    if (tid < N_KDE)
        partials[tid * N_BLOCKS + blockIdx.x] =
            (sm[tid] + sm[N_KDE + tid]) + (sm[2 * N_KDE + tid] + sm[3 * N_KDE + tid]);
}

// ---------------------------------------------------------------------------
// Kernel B: reduce per-block KDE partials -> kde[45]; write scalar output 0.0
// ---------------------------------------------------------------------------
__global__ __launch_bounds__(256)
void k_kde_reduce(const float* __restrict__ partials, float* __restrict__ kde,
                  float* __restrict__ out_scalar)
{
    const int l = blockIdx.x, t = threadIdx.x;
    float s = (partials[l * N_BLOCKS + t]       + partials[l * N_BLOCKS + 256 + t])
            + (partials[l * N_BLOCKS + 512 + t] + partials[l * N_BLOCKS + 768 + t]);
    __shared__ float sm[256];
    sm[t] = s;
    __syncthreads();
#pragma unroll
    for (int off = 128; off > 0; off >>= 1) {
        if (t < off) sm[t] += sm[t + off];
        __syncthreads();
    }
    if (t == 0) kde[l] = sm[0];
    if (l == 0 && t == 0) out_scalar[0] = 0.0f;
}

// ---------------------------------------------------------------------------
// Kernel C: scaled centers (per-block, LDS), argmin quantize, z_q = q@W_e+b_e
// ---------------------------------------------------------------------------
__global__ __launch_bounds__(256)
void k_quant_out(const float* __restrict__ zc, const float* __restrict__ kde,
                 const float* __restrict__ centers, const float* __restrict__ We,
                 const float* __restrict__ be, float* __restrict__ out)
{
    __shared__ float sc[N_KDE];
    const int tid = threadIdx.x;
    if (tid < N_KDE) {
        const int c = tid / 15;
        float s = 0.f;
        for (int j = 0; j < 15; ++j) s += kde[c * 15 + j];  // weights_sum, numpy order
        sc[tid] = (centers[tid] * kde[tid]) / s;
    }
    __syncthreads();

    const int lane = tid & 63;
    const int wid  = tid >> 6;
    const int gw   = blockIdx.x * 4 + wid;

    // Preload W_e fragment (W_e is [3][768] row-major) and b_e fragment
    float we[3][4][3], beL[3][4];
#pragma unroll
    for (int seg = 0; seg < 3; ++seg)
#pragma unroll
        for (int m = 0; m < 4; ++m) {
            const int k = seg * 256 + lane * 4 + m;
#pragma unroll
            for (int c = 0; c < 3; ++c) we[seg][m][c] = We[c * N_CIN + k];
            beL[seg][m] = be[k];
        }

    for (int i = 0; i < RPW; ++i) {
        const int row = gw + N_WAVES * i;
        float q[3];
#pragma unroll
        for (int c = 0; c < 3; ++c) {
            const float zv = zc[(size_t)row * 3 + c];
            int   best = 0;
            float bd   = fabsf(zv - sc[c * 15]);
#pragma unroll
            for (int j = 1; j < 15; ++j) {
                const float d = fabsf(zv - sc[c * 15 + j]);
                if (d < bd) { bd = d; best = j; }   // strict <: first-min wins (np.argmin)
            }
            q[c] = sc[c * 15 + best];
        }
        float4* orow = (float4*)(out + (size_t)row * N_CIN);
#pragma unroll
        for (int seg = 0; seg < 3; ++seg) {
            float4 o;
            float t0, t1, t2, t3;
            t0 = q[0] * we[seg][0][0]; t0 = fmaf(q[1], we[seg][0][1], t0);
            t0 = fmaf(q[2], we[seg][0][2], t0); o.x = t0 + beL[seg][0];
            t1 = q[0] * we[seg][1][0]; t1 = fmaf(q[1], we[seg][1][1], t1);
            t1 = fmaf(q[2], we[seg][1][2], t1); o.y = t1 + beL[seg][1];
            t2 = q[0] * we[seg][2][0]; t2 = fmaf(q[1], we[seg][2][1], t2);
            t2 = fmaf(q[2], we[seg][2][2], t2); o.z = t2 + beL[seg][2];
            t3 = q[0] * we[seg][3][0]; t3 = fmaf(q[1], we[seg][3][1], t3);
            t3 = fmaf(q[2], we[seg][3][2], t3); o.w = t3 + beL[seg][3];
            orow[seg * 64 + lane] = o;
        }
    }
}

// ---------------------------------------------------------------------------
extern "C" void kernel_launch(void* const* d_in, const int* in_sizes, int n_in,
                              void* d_out, int out_size, void* d_ws, size_t ws_size,
                              hipStream_t stream)
{
    const float* z       = (const float*)d_in[0];   // (32,4096,768)
    const float* Wc      = (const float*)d_in[1];   // (768,3)
    const float* bc      = (const float*)d_in[2];   // (3,)
    const float* We      = (const float*)d_in[3];   // (3,768)
    const float* be      = (const float*)d_in[4];   // (768,)
    const float* centers = (const float*)d_in[5];   // (3,15)

    float* out = (float*)d_out;                      // z_q flat + trailing scalar
    float* ws  = (float*)d_ws;
    float* zc       = ws + WS_ZC_OFF;
    float* partials = ws + WS_PART_OFF;
    float* kde      = ws + WS_KDE_OFF;

    k_zc_kde<<<N_BLOCKS, 256, 0, stream>>>(z, Wc, bc, centers, zc, partials);
    k_kde_reduce<<<N_KDE, 256, 0, stream>>>(partials, kde, out + (out_size - 1));
    k_quant_out<<<N_BLOCKS, 256, 0, stream>>>(zc, kde, centers, We, be, out);
}